// Round 1
// baseline (678.049 us; speedup 1.0000x reference)
//
#include <hip/hip_runtime.h>
#include <stdint.h>

// Problem constants (fixed by setup_inputs)
#define B_N   8
#define S_N   2048
#define D_N   1024
#define A_N   512
#define DV_N  512

typedef __attribute__((ext_vector_type(8))) short bf16x8;
typedef __attribute__((ext_vector_type(4))) float f32x4;

__device__ __forceinline__ unsigned short f2bf(float x) {
    union { float f; unsigned int u; } v; v.f = x;
    return (unsigned short)((v.u + 0x7fffu + ((v.u >> 16) & 1u)) >> 16);
}
__device__ __forceinline__ float bf2f(unsigned short h) {
    union { unsigned int u; float f; } v; v.u = ((unsigned int)h) << 16;
    return v.f;
}

// z-indexed triple fp32->bf16 converter (used for Q,K,V and for the 3 weights)
__global__ void cvt3_f32_bf16(const float* __restrict__ s0, const float* __restrict__ s1,
                              const float* __restrict__ s2,
                              unsigned short* __restrict__ d0, unsigned short* __restrict__ d1,
                              unsigned short* __restrict__ d2, int n4) {
    const float* s = (blockIdx.z == 0) ? s0 : (blockIdx.z == 1) ? s1 : s2;
    unsigned short* d = (blockIdx.z == 0) ? d0 : (blockIdx.z == 1) ? d1 : d2;
    int i = blockIdx.x * blockDim.x + threadIdx.x;
    if (i >= n4) return;
    float4 v = ((const float4*)s)[i];
    ushort4 o;
    o.x = f2bf(v.x); o.y = f2bf(v.y); o.z = f2bf(v.z); o.w = f2bf(v.w);
    ((ushort4*)d)[i] = o;
}

__global__ void zero_f32(float* __restrict__ p, int n) {
    int i = blockIdx.x * blockDim.x + threadIdx.x;
    if (i < n) p[i] = 0.0f;
}

__device__ __forceinline__ void gld_lds16(const void* g, void* l) {
    __builtin_amdgcn_global_load_lds(
        (const __attribute__((address_space(1))) unsigned int*)g,
        (__attribute__((address_space(3))) unsigned int*)l, 16, 0, 0);
}

// Bit-pack the transposed mask: mpT[b][k][w] bit q%32 of word q/32 = mask[b][q][k].
__global__ __launch_bounds__(256) void pack_maskT(const int* __restrict__ mask,
                                                  unsigned int* __restrict__ mpT) {
    __shared__ int tile[64 * 129];
    const int b  = blockIdx.z;
    const int q0 = blockIdx.y * 64;
    const int k0 = blockIdx.x * 128;
    const int tid = threadIdx.x;
    const long long base = (long long)b * S_N * S_N;
#pragma unroll
    for (int it = 0; it < 8; ++it) {
        int c = it * 256 + tid;
        int row  = c >> 5;
        int col4 = (c & 31) * 4;
        int4 v = *(const int4*)&mask[base + (long long)(q0 + row) * S_N + k0 + col4];
        int* d = &tile[row * 129 + col4];
        d[0] = v.x; d[1] = v.y; d[2] = v.z; d[3] = v.w;
    }
    __syncthreads();
    const int wave = tid >> 6, lane = tid & 63;
#pragma unroll
    for (int kk = 0; kk < 32; ++kk) {
        const int k = wave * 32 + kk;
        const int v = tile[lane * 129 + k];
        const unsigned long long bal = __ballot(v != 0);
        if (lane == 0) {
            unsigned int* o = &mpT[(long long)(b * S_N + k0 + k) * 64 + (q0 >> 5)];
            o[0] = (unsigned int)bal;
            o[1] = (unsigned int)(bal >> 32);
        }
    }
}

// NT GEMM: C[m,n] = sum_k A[m,k]*B[n,k]
// MODE 0: bf16 out + bias[col]; dual-weight: blockIdx.y>=128 -> B2/bias2 (fused Q&K proj)
// MODE 1: bf16 out + bias[row]              (WV^T projection, batched)
// MODE 2: e = exp(acc*scale) masked; bf16 out; rowsum atomics   (scores^T)
// MODE 3: f32 out, row-scaled by 1/rowsum   (final attn @ WV)
template <int MODE>
__global__ __launch_bounds__(256) void gemm_nt(
    const unsigned short* __restrict__ A, const unsigned short* __restrict__ B,
    const unsigned short* __restrict__ B2,
    void* __restrict__ C, const float* __restrict__ bias, const float* __restrict__ bias2,
    const unsigned int* __restrict__ mpT, float* __restrict__ rowsum,
    int M, int N, int K,
    long long sA, long long sB, long long sC, float scale)
{
    __shared__ __align__(16) unsigned short As[128 * 32];
    __shared__ __align__(16) unsigned short Bs[128 * 32];

    const int tid  = threadIdx.x;
    const int wave = tid >> 6;
    const int lane = tid & 63;
    const int lrow = lane & 15;
    const int quad = lane >> 4;
    const int wm = wave & 1;
    const int wn = wave >> 1;
    const int b  = blockIdx.z;
    const int m0 = blockIdx.y * 128;
    const int n0 = blockIdx.x * 128;

    const unsigned short* Ab = A + (long long)b * sA;
    const unsigned short* Bsel = (MODE == 0 && blockIdx.y >= 128) ? B2 : B;
    const unsigned short* Bb = Bsel + (long long)b * sB;
    const float* bias_s = (MODE == 0 && blockIdx.y >= 128) ? bias2 : bias;

    f32x4 acc[4][4];
#pragma unroll
    for (int i = 0; i < 4; ++i)
#pragma unroll
        for (int j = 0; j < 4; ++j) acc[i][j] = (f32x4){0.f, 0.f, 0.f, 0.f};

    const int srow = lane >> 2;        // row within 16-row segment
    const int scol = (lane & 3) * 8;   // k-element offset (8 bf16 = 16B)

    for (int kt = 0; kt < K; kt += 32) {
#pragma unroll
        for (int t = 0; t < 2; ++t) {
            const int seg = t * 4 + wave;
            const unsigned short* ga =
                Ab + (long long)(m0 + seg * 16 + srow) * K + kt + scol;
            gld_lds16(ga, &As[seg * 16 * 32]);
            const unsigned short* gb =
                Bb + (long long)(n0 + seg * 16 + srow) * K + kt + scol;
            gld_lds16(gb, &Bs[seg * 16 * 32]);
        }
        __syncthreads();

        bf16x8 af[4], bfr[4];
#pragma unroll
        for (int i = 0; i < 4; ++i)
            af[i] = *(const bf16x8*)&As[(wm * 64 + i * 16 + lrow) * 32 + quad * 8];
#pragma unroll
        for (int j = 0; j < 4; ++j)
            bfr[j] = *(const bf16x8*)&Bs[(wn * 64 + j * 16 + lrow) * 32 + quad * 8];
#pragma unroll
        for (int i = 0; i < 4; ++i)
#pragma unroll
            for (int j = 0; j < 4; ++j)
                acc[i][j] = __builtin_amdgcn_mfma_f32_16x16x32_bf16(
                    af[i], bfr[j], acc[i][j], 0, 0, 0);
        __syncthreads();
    }

    // Epilogue. C/D layout (verified): col = lane&15, row = quad*4 + reg.
    if (MODE == 0 || MODE == 1) {
#pragma unroll
        for (int i = 0; i < 4; ++i) {
            const int rowb = m0 + wm * 64 + i * 16 + quad * 4;
#pragma unroll
            for (int j = 0; j < 4; ++j) {
                const int col = n0 + wn * 64 + j * 16 + lrow;
#pragma unroll
                for (int r = 0; r < 4; ++r) {
                    const int row = rowb + r;
                    float v = acc[i][j][r];
                    v += (MODE == 0) ? bias_s[col] : bias_s[row];
                    (((unsigned short*)C) + (long long)b * sC)
                        [(long long)row * N + col] = f2bf(v);
                }
            }
        }
    } else if (MODE == 2) {
        unsigned short* Cb = ((unsigned short*)C) + (long long)b * sC;
        const unsigned int* mpb = mpT + ((long long)b * S_N) * 64;
        float* rs = rowsum + (long long)b * S_N;
#pragma unroll
        for (int i = 0; i < 4; ++i) {
#pragma unroll
            for (int r = 0; r < 4; ++r) {
                const int row = m0 + wm * 64 + i * 16 + quad * 4 + r;
                const unsigned int* mpr = mpb + (long long)row * 64;
                float rsum = 0.0f;
#pragma unroll
                for (int j = 0; j < 4; ++j) {
                    const int col = n0 + wn * 64 + j * 16 + lrow;
                    const float v = acc[i][j][r] * scale;
                    const unsigned int w = mpr[col >> 5];
                    const float e = ((w >> (col & 31)) & 1u) ? 0.0f : __expf(v);
                    const unsigned short h = f2bf(e);
                    Cb[(long long)row * S_N + col] = h;
                    rsum += bf2f(h);   // sum the rounded values for consistency
                }
                rsum += __shfl_xor(rsum, 1);
                rsum += __shfl_xor(rsum, 2);
                rsum += __shfl_xor(rsum, 4);
                rsum += __shfl_xor(rsum, 8);
                if (lrow == 0) atomicAdd(&rs[row], rsum);
            }
        }
    } else {  // MODE 3
        float* Cb = ((float*)C) + (long long)b * sC;
        const float* rs = rowsum + (long long)b * S_N;
#pragma unroll
        for (int i = 0; i < 4; ++i) {
#pragma unroll
            for (int r = 0; r < 4; ++r) {
                const int row = m0 + wm * 64 + i * 16 + quad * 4 + r;
                const float inv = 1.0f / rs[row];
#pragma unroll
                for (int j = 0; j < 4; ++j) {
                    const int col = n0 + wn * 64 + j * 16 + lrow;
                    Cb[(long long)row * N + col] = acc[i][j][r] * inv;
                }
            }
        }
    }
}

// attn[row][q] = bf16e[row][q] / rowsum[row]  (fp32 write to d_out attn region)
__global__ __launch_bounds__(256) void normalize_rows(
    const unsigned short* __restrict__ ebf, const float* __restrict__ rowsum,
    float* __restrict__ attn)
{
    const long long row = blockIdx.x;
    const float inv = 1.0f / rowsum[row];
    const ushort4* src = (const ushort4*)(ebf + row * S_N);
    float4* dst = (float4*)(attn + row * S_N);
    const int tid = threadIdx.x;
#pragma unroll
    for (int t = 0; t < 2; ++t) {
        ushort4 h = src[tid + t * 256];
        float4 o;
        o.x = bf2f(h.x) * inv;
        o.y = bf2f(h.y) * inv;
        o.z = bf2f(h.z) * inv;
        o.w = bf2f(h.w) * inv;
        dst[tid + t * 256] = o;
    }
}

extern "C" void kernel_launch(void* const* d_in, const int* in_sizes, int n_in,
                              void* d_out, int out_size, void* d_ws, size_t ws_size,
                              hipStream_t stream) {
    const float* Q    = (const float*)d_in[0];
    const float* K    = (const float*)d_in[1];
    const float* V    = (const float*)d_in[2];
    const int*   mask = (const int*)d_in[3];
    const float* Wq   = (const float*)d_in[4];
    const float* bq   = (const float*)d_in[5];
    const float* Wk   = (const float*)d_in[6];
    const float* bk   = (const float*)d_in[7];
    const float* Wv   = (const float*)d_in[8];
    const float* bv   = (const float*)d_in[9];

    float* out      = (float*)d_out;                              // [B,S,Dv]
    float* attn_out = out + (long long)B_N * S_N * DV_N;          // [B,S,S]

    // Workspace layout. Qbf||Kbf contiguous (fused QK proj reads rows 0..32767);
    // attn_bf (67.1MB, bf16 e-values) overlays Qbf+Kbf after the projections.
    unsigned short* Qbf  = (unsigned short*)d_ws;
    unsigned short* Kbf  = Qbf + (long long)B_N * S_N * D_N;
    unsigned short* attn_bf = Qbf;  // overlay
    unsigned short* Vbf  = Kbf + (long long)B_N * S_N * D_N;
    unsigned short* Wqbf = Vbf + (long long)B_N * S_N * D_N;
    unsigned short* Wkbf = Wqbf + (long long)A_N * D_N;
    unsigned short* Wvbf = Wkbf + (long long)A_N * D_N;
    unsigned short* Qp   = Wvbf + (long long)DV_N * D_N;   // Qp||Kp contiguous
    unsigned short* Kp   = Qp + (long long)B_N * S_N * A_N;
    unsigned short* WVt  = Kp + (long long)B_N * S_N * A_N;
    unsigned int*   mpT  = (unsigned int*)(WVt + (long long)B_N * DV_N * S_N); // 4 MB
    float*          rowsum = (float*)(mpT + (long long)B_N * S_N * 64);        // 64 KB

    const float scale = 0.044194173824159216f;  // 1/sqrt(512)

    // 0) zero rowsum (ws is poisoned each call) + pack transposed mask bits
    zero_f32<<<dim3((B_N * S_N) / 256), dim3(256), 0, stream>>>(rowsum, B_N * S_N);
    pack_maskT<<<dim3(S_N / 128, S_N / 64, B_N), dim3(256), 0, stream>>>(mask, mpT);

    // 1) fp32 -> bf16: Q,K,V in one dispatch; 3 weights in one dispatch
    {
        int n4 = (int)((long long)B_N * S_N * D_N / 4);
        cvt3_f32_bf16<<<dim3((n4 + 255) / 256, 1, 3), dim3(256), 0, stream>>>(
            Q, K, V, Qbf, Kbf, Vbf, n4);
        int w4 = (int)((long long)A_N * D_N / 4);
        cvt3_f32_bf16<<<dim3((w4 + 255) / 256, 1, 3), dim3(256), 0, stream>>>(
            Wq, Wk, Wv, Wqbf, Wkbf, Wvbf, w4);
    }

    // 2) fused Q&K projections: rows 0..16383 -> Qp (Wq,bq), 16384..32767 -> Kp (Wk,bk)
    gemm_nt<0><<<dim3(A_N / 128, (2 * B_N * S_N) / 128, 1), dim3(256), 0, stream>>>(
        Qbf, Wqbf, Wkbf, (void*)Qp, bq, bk, nullptr, nullptr,
        2 * B_N * S_N, A_N, D_N, 0, 0, 0, 1.0f);
    // 3) WVt[b] = (V[b] @ Wv^T + bv)^T : M=Dv rows, N=S cols
    gemm_nt<1><<<dim3(S_N / 128, DV_N / 128, B_N), dim3(256), 0, stream>>>(
        Wvbf, Vbf, nullptr, (void*)WVt, bv, nullptr, nullptr, nullptr,
        DV_N, S_N, D_N, 0, (long long)S_N * D_N, (long long)DV_N * S_N, 1.0f);
    // 4) e[b,k,q] = exp(scale*Kp.Qp) masked -> bf16 attn_bf; rowsum atomics
    gemm_nt<2><<<dim3(S_N / 128, S_N / 128, B_N), dim3(256), 0, stream>>>(
        Kp, Qp, nullptr, (void*)attn_bf, nullptr, nullptr, mpT, rowsum,
        S_N, S_N, A_N, (long long)S_N * A_N, (long long)S_N * A_N,
        (long long)S_N * S_N, scale);
    // 5) attn fp32 = e / rowsum -> d_out attn region
    normalize_rows<<<dim3(B_N * S_N), dim3(256), 0, stream>>>(attn_bf, rowsum, attn_out);
    // 6) selfOutput[b,k,v] = (sum_q e[b,k,q] * WVt[b,v,q]) / rowsum[b,k]
    gemm_nt<3><<<dim3(DV_N / 128, S_N / 128, B_N), dim3(256), 0, stream>>>(
        attn_bf, WVt, nullptr, (void*)out, nullptr, nullptr, nullptr, rowsum,
        S_N, DV_N, S_N, (long long)S_N * S_N, (long long)DV_N * S_N,
        (long long)S_N * DV_N, 1.0f);
}

// Round 2
// 644.179 us; speedup vs baseline: 1.0526x; 1.0526x over previous
//
#include <hip/hip_runtime.h>
#include <stdint.h>

// Problem constants (fixed by setup_inputs)
#define B_N   8
#define S_N   2048
#define D_N   1024
#define A_N   512
#define DV_N  512

typedef __attribute__((ext_vector_type(8))) short bf16x8;
typedef __attribute__((ext_vector_type(4))) float f32x4;

__device__ __forceinline__ unsigned short f2bf(float x) {
    union { float f; unsigned int u; } v; v.f = x;
    return (unsigned short)((v.u + 0x7fffu + ((v.u >> 16) & 1u)) >> 16);
}
__device__ __forceinline__ float bf2f(unsigned short h) {
    union { unsigned int u; float f; } v; v.u = ((unsigned int)h) << 16;
    return v.f;
}

// z-indexed triple fp32->bf16 converter (used for Q,K,V and for the 3 weights)
__global__ void cvt3_f32_bf16(const float* __restrict__ s0, const float* __restrict__ s1,
                              const float* __restrict__ s2,
                              unsigned short* __restrict__ d0, unsigned short* __restrict__ d1,
                              unsigned short* __restrict__ d2, int n4) {
    const float* s = (blockIdx.z == 0) ? s0 : (blockIdx.z == 1) ? s1 : s2;
    unsigned short* d = (blockIdx.z == 0) ? d0 : (blockIdx.z == 1) ? d1 : d2;
    int i = blockIdx.x * blockDim.x + threadIdx.x;
    if (i >= n4) return;
    float4 v = ((const float4*)s)[i];
    ushort4 o;
    o.x = f2bf(v.x); o.y = f2bf(v.y); o.z = f2bf(v.z); o.w = f2bf(v.w);
    ((ushort4*)d)[i] = o;
}

__global__ void zero_f32(float* __restrict__ p, int n) {
    int i = blockIdx.x * blockDim.x + threadIdx.x;
    if (i < n) p[i] = 0.0f;
}

__device__ __forceinline__ void gld_lds16(const void* g, void* l) {
    __builtin_amdgcn_global_load_lds(
        (const __attribute__((address_space(1))) unsigned int*)g,
        (__attribute__((address_space(3))) unsigned int*)l, 16, 0, 0);
}

// Bit-pack the transposed mask: mpT[b][k][w] bit q%32 of word q/32 = mask[b][q][k].
__global__ __launch_bounds__(256) void pack_maskT(const int* __restrict__ mask,
                                                  unsigned int* __restrict__ mpT) {
    __shared__ int tile[64 * 129];
    const int b  = blockIdx.z;
    const int q0 = blockIdx.y * 64;
    const int k0 = blockIdx.x * 128;
    const int tid = threadIdx.x;
    const long long base = (long long)b * S_N * S_N;
#pragma unroll
    for (int it = 0; it < 8; ++it) {
        int c = it * 256 + tid;
        int row  = c >> 5;
        int col4 = (c & 31) * 4;
        int4 v = *(const int4*)&mask[base + (long long)(q0 + row) * S_N + k0 + col4];
        int* d = &tile[row * 129 + col4];
        d[0] = v.x; d[1] = v.y; d[2] = v.z; d[3] = v.w;
    }
    __syncthreads();
    const int wave = tid >> 6, lane = tid & 63;
#pragma unroll
    for (int kk = 0; kk < 32; ++kk) {
        const int k = wave * 32 + kk;
        const int v = tile[lane * 129 + k];
        const unsigned long long bal = __ballot(v != 0);
        if (lane == 0) {
            unsigned int* o = &mpT[(long long)(b * S_N + k0 + k) * 64 + (q0 >> 5)];
            o[0] = (unsigned int)bal;
            o[1] = (unsigned int)(bal >> 32);
        }
    }
}

// ---------------------------------------------------------------------------
// OLD 128x128 single-buffered GEMM (kept for MODE 1 and MODE 3)
// ---------------------------------------------------------------------------
template <int MODE>
__global__ __launch_bounds__(256) void gemm_nt(
    const unsigned short* __restrict__ A, const unsigned short* __restrict__ B,
    const unsigned short* __restrict__ B2,
    void* __restrict__ C, const float* __restrict__ bias, const float* __restrict__ bias2,
    const unsigned int* __restrict__ mpT, float* __restrict__ rowsum,
    int M, int N, int K,
    long long sA, long long sB, long long sC, float scale)
{
    __shared__ __align__(16) unsigned short As[128 * 32];
    __shared__ __align__(16) unsigned short Bs[128 * 32];

    const int tid  = threadIdx.x;
    const int wave = tid >> 6;
    const int lane = tid & 63;
    const int lrow = lane & 15;
    const int quad = lane >> 4;
    const int wm = wave & 1;
    const int wn = wave >> 1;
    const int b  = blockIdx.z;
    const int m0 = blockIdx.y * 128;
    const int n0 = blockIdx.x * 128;

    const unsigned short* Ab = A + (long long)b * sA;
    const unsigned short* Bsel = (MODE == 0 && blockIdx.y >= 128) ? B2 : B;
    const unsigned short* Bb = Bsel + (long long)b * sB;
    const float* bias_s = (MODE == 0 && blockIdx.y >= 128) ? bias2 : bias;

    f32x4 acc[4][4];
#pragma unroll
    for (int i = 0; i < 4; ++i)
#pragma unroll
        for (int j = 0; j < 4; ++j) acc[i][j] = (f32x4){0.f, 0.f, 0.f, 0.f};

    const int srow = lane >> 2;        // row within 16-row segment
    const int scol = (lane & 3) * 8;   // k-element offset (8 bf16 = 16B)

    for (int kt = 0; kt < K; kt += 32) {
#pragma unroll
        for (int t = 0; t < 2; ++t) {
            const int seg = t * 4 + wave;
            const unsigned short* ga =
                Ab + (long long)(m0 + seg * 16 + srow) * K + kt + scol;
            gld_lds16(ga, &As[seg * 16 * 32]);
            const unsigned short* gb =
                Bb + (long long)(n0 + seg * 16 + srow) * K + kt + scol;
            gld_lds16(gb, &Bs[seg * 16 * 32]);
        }
        __syncthreads();

        bf16x8 af[4], bfr[4];
#pragma unroll
        for (int i = 0; i < 4; ++i)
            af[i] = *(const bf16x8*)&As[(wm * 64 + i * 16 + lrow) * 32 + quad * 8];
#pragma unroll
        for (int j = 0; j < 4; ++j)
            bfr[j] = *(const bf16x8*)&Bs[(wn * 64 + j * 16 + lrow) * 32 + quad * 8];
#pragma unroll
        for (int i = 0; i < 4; ++i)
#pragma unroll
            for (int j = 0; j < 4; ++j)
                acc[i][j] = __builtin_amdgcn_mfma_f32_16x16x32_bf16(
                    af[i], bfr[j], acc[i][j], 0, 0, 0);
        __syncthreads();
    }

    if (MODE == 0 || MODE == 1) {
#pragma unroll
        for (int i = 0; i < 4; ++i) {
            const int rowb = m0 + wm * 64 + i * 16 + quad * 4;
#pragma unroll
            for (int j = 0; j < 4; ++j) {
                const int col = n0 + wn * 64 + j * 16 + lrow;
#pragma unroll
                for (int r = 0; r < 4; ++r) {
                    const int row = rowb + r;
                    float v = acc[i][j][r];
                    v += (MODE == 0) ? bias_s[col] : bias_s[row];
                    (((unsigned short*)C) + (long long)b * sC)
                        [(long long)row * N + col] = f2bf(v);
                }
            }
        }
    } else if (MODE == 2) {
        unsigned short* Cb = ((unsigned short*)C) + (long long)b * sC;
        const unsigned int* mpb = mpT + ((long long)b * S_N) * 64;
        float* rs = rowsum + (long long)b * S_N;
#pragma unroll
        for (int i = 0; i < 4; ++i) {
#pragma unroll
            for (int r = 0; r < 4; ++r) {
                const int row = m0 + wm * 64 + i * 16 + quad * 4 + r;
                const unsigned int* mpr = mpb + (long long)row * 64;
                float rsum = 0.0f;
#pragma unroll
                for (int j = 0; j < 4; ++j) {
                    const int col = n0 + wn * 64 + j * 16 + lrow;
                    const float v = acc[i][j][r] * scale;
                    const unsigned int w = mpr[col >> 5];
                    const float e = ((w >> (col & 31)) & 1u) ? 0.0f : __expf(v);
                    const unsigned short h = f2bf(e);
                    Cb[(long long)row * S_N + col] = h;
                    rsum += bf2f(h);
                }
                rsum += __shfl_xor(rsum, 1);
                rsum += __shfl_xor(rsum, 2);
                rsum += __shfl_xor(rsum, 4);
                rsum += __shfl_xor(rsum, 8);
                if (lrow == 0) atomicAdd(&rs[row], rsum);
            }
        }
    } else {  // MODE 3
        float* Cb = ((float*)C) + (long long)b * sC;
        const float* rs = rowsum + (long long)b * S_N;
#pragma unroll
        for (int i = 0; i < 4; ++i) {
#pragma unroll
            for (int r = 0; r < 4; ++r) {
                const int row = m0 + wm * 64 + i * 16 + quad * 4 + r;
                const float inv = 1.0f / rs[row];
#pragma unroll
                for (int j = 0; j < 4; ++j) {
                    const int col = n0 + wn * 64 + j * 16 + lrow;
                    Cb[(long long)row * N + col] = acc[i][j][r] * inv;
                }
            }
        }
    }
}

// ---------------------------------------------------------------------------
// NEW 256x256 / BK=64 / 8-wave / 8-phase pipelined GEMM (T2+T3+T4+T5).
// LDS 128 KiB dynamic: A[2 parity][2 half][128x64] then B same, bf16.
// Staging: quarter-granular (16 KB = 2 gld_lds/wave), one quarter per phase,
// issued the phase AFTER the target region's last ds_read (WAR-safe via the
// inter-phase barrier). Counted vmcnt (6/10/8, never 0) gives >=4 phases of
// load lead time (RAW-safe: own-wait + barrier covers other waves' chunks).
// LDS read swizzle: colByte ^= ((row&7)<<4)  (8-way spread -> 2-way residual,
// free). gld_lds dest stays linear; the SOURCE address carries the inverse
// swizzle (rule: both-sides-or-neither).
// ---------------------------------------------------------------------------
#define VMCNT(n) asm volatile("s_waitcnt vmcnt(" #n ")" ::: "memory")

template <int MODE>
__global__ __launch_bounds__(512, 2) void gemm_nt8(
    const unsigned short* __restrict__ A, const unsigned short* __restrict__ B,
    const unsigned short* __restrict__ B2,
    void* __restrict__ C, const float* __restrict__ bias, const float* __restrict__ bias2,
    const unsigned int* __restrict__ mpT, float* __restrict__ rowsum,
    int M, int N, int K,
    long long sA, long long sB, long long sC, float scale)
{
    extern __shared__ unsigned short sm[];   // 65536 ushorts = 128 KiB

    const int tid  = threadIdx.x;
    const int w    = tid >> 6;
    const int lane = tid & 63;
    const int lrow = lane & 15;
    const int quad = lane >> 4;
    const int wmSel = w >> 2;        // compute A-half (M half)
    const int wn    = w & 3;         // compute N quarter (64 cols)
    const int bhSel = wn >> 1;       // compute B-half
    const int b  = blockIdx.z;
    const int m0 = blockIdx.y * 256;
    const int n0 = blockIdx.x * 256;

    const unsigned short* Ab = A + (long long)b * sA;
    const unsigned short* Bsel = (MODE == 0 && blockIdx.y >= 64) ? B2 : B;
    const unsigned short* Bb = Bsel + (long long)b * sB;
    const float* bias_s = (MODE == 0 && blockIdx.y >= 64) ? bias2 : bias;

    // read-side swizzle constants (byte): colByte(kk) = (kk<<6|quad<<4) ^ ((lrow&7)<<4)
    const int csw0 = ((quad ^ (lrow & 7)) << 4);
    const int csw1 = csw0 ^ 64;
    // stage-side inverse swizzle (element offset within the row's 64-col K-tile)
    const int cswSt = (((lane & 7) ^ (lane >> 3)) << 3);

    // per-lane staging source bases (row component is lane/wave-constant)
    const unsigned short* srcA =
        Ab + (size_t)(m0 + (w >> 2) * 128 + (w & 3) * 16 + (lane >> 3)) * K + cswSt;
    const unsigned short* srcB =
        Bb + (size_t)(n0 + (w >> 2) * 128 + ((w >> 1) & 1) * 64 + (w & 1) * 16 + (lane >> 3)) * K + cswSt;

#define STAGE_A(par, mq, tk) do {                                              \
        const unsigned short* s_ = srcA + (size_t)(mq) * 64 * K + (size_t)(tk) * 64; \
        unsigned short* d_ = &sm[(par) * 16384 + (w >> 2) * 8192 +             \
                                 ((mq) * 64 + (w & 3) * 16) * 64];             \
        gld_lds16(s_, d_);                                                     \
        gld_lds16(s_ + 8 * (size_t)K, d_ + 8 * 64);                            \
    } while (0)

#define STAGE_B(par, nq, tk) do {                                              \
        const unsigned short* s_ = srcB + (size_t)(nq) * 32 * K + (size_t)(tk) * 64; \
        unsigned short* d_ = &sm[32768 + (par) * 16384 + (w >> 2) * 8192 +     \
                                 (((w >> 1) & 1) * 64 + (nq) * 32 + (w & 1) * 16) * 64]; \
        gld_lds16(s_, d_);                                                     \
        gld_lds16(s_ + 8 * (size_t)K, d_ + 8 * 64);                            \
    } while (0)

    f32x4 acc[8][4];
#pragma unroll
    for (int i = 0; i < 8; ++i)
#pragma unroll
        for (int j = 0; j < 4; ++j) acc[i][j] = (f32x4){0.f, 0.f, 0.f, 0.f};

#define PHASE(par, mq, nq, STAGE_STMT, WAIT_STMT) do {                         \
        bf16x8 af[4][2], bfr[2][2];                                            \
        const int abase_ = (par) * 16384 + wmSel * 8192 + (mq) * 4096;         \
        _Pragma("unroll")                                                      \
        for (int m_ = 0; m_ < 4; ++m_) {                                       \
            af[m_][0] = *(const bf16x8*)&sm[abase_ + (m_ * 16 + lrow) * 64 + (csw0 >> 1)]; \
            af[m_][1] = *(const bf16x8*)&sm[abase_ + (m_ * 16 + lrow) * 64 + (csw1 >> 1)]; \
        }                                                                      \
        const int bbase_ = 32768 + (par) * 16384 + bhSel * 8192 +              \
                           ((wn & 1) * 64 + (nq) * 32) * 64;                   \
        _Pragma("unroll")                                                      \
        for (int n_ = 0; n_ < 2; ++n_) {                                       \
            bfr[n_][0] = *(const bf16x8*)&sm[bbase_ + (n_ * 16 + lrow) * 64 + (csw0 >> 1)]; \
            bfr[n_][1] = *(const bf16x8*)&sm[bbase_ + (n_ * 16 + lrow) * 64 + (csw1 >> 1)]; \
        }                                                                      \
        STAGE_STMT;                                                            \
        WAIT_STMT;                                                             \
        __builtin_amdgcn_s_barrier();                                          \
        __builtin_amdgcn_s_setprio(1);                                         \
        _Pragma("unroll")                                                      \
        for (int m_ = 0; m_ < 4; ++m_)                                         \
            _Pragma("unroll")                                                  \
            for (int n_ = 0; n_ < 2; ++n_) {                                   \
                acc[(mq)*4+m_][(nq)*2+n_] = __builtin_amdgcn_mfma_f32_16x16x32_bf16( \
                    af[m_][0], bfr[n_][0], acc[(mq)*4+m_][(nq)*2+n_], 0, 0, 0); \
                acc[(mq)*4+m_][(nq)*2+n_] = __builtin_amdgcn_mfma_f32_16x16x32_bf16( \
                    af[m_][1], bfr[n_][1], acc[(mq)*4+m_][(nq)*2+n_], 0, 0, 0); \
            }                                                                  \
        __builtin_amdgcn_s_setprio(0);                                         \
        __builtin_amdgcn_s_barrier();                                          \
    } while (0)

    const int NT = K >> 6;   // K-tiles of 64 (NT even, >= 4 for all call sites)

    // Prologue: tile0 {A0,B0,A1,B1}, tile1 {A0,B0}  -> 12 loads/wave.
    STAGE_A(0, 0, 0); STAGE_B(0, 0, 0);
    STAGE_A(0, 1, 0); STAGE_B(0, 1, 0);
    STAGE_A(1, 0, 1); STAGE_B(1, 0, 1);
    VMCNT(8);                       // tile0 A0,B0 landed
    __builtin_amdgcn_s_barrier();

    for (int t = 0; t < NT; t += 2) {
        const int t2 = (t + 2 < NT) ? t + 2 : NT - 1;   // clamped (last iter re-reads)
        const int t3 = (t + 3 < NT) ? t + 3 : NT - 1;
        PHASE(0, 0, 0, STAGE_A(1, 1, t + 1), VMCNT(6));
        PHASE(0, 0, 1, STAGE_B(1, 1, t + 1), VMCNT(10));
        PHASE(0, 1, 0, STAGE_A(0, 0, t2),    (void)0);
        PHASE(0, 1, 1, STAGE_B(0, 0, t2),    VMCNT(8));
        PHASE(1, 0, 0, STAGE_A(0, 1, t2),    VMCNT(6));
        PHASE(1, 0, 1, STAGE_B(0, 1, t2),    VMCNT(10));
        PHASE(1, 1, 0, STAGE_A(1, 0, t3),    (void)0);
        PHASE(1, 1, 1, STAGE_B(1, 0, t3),    VMCNT(8));
    }
    VMCNT(0);   // drain staging before exit (LDS dealloc safety)

    // Epilogue. C/D layout: col = lane&15, row = quad*4 + reg.
    if (MODE == 0) {
#pragma unroll
        for (int i = 0; i < 8; ++i) {
            const int rowb = m0 + wmSel * 128 + i * 16 + quad * 4;
#pragma unroll
            for (int j = 0; j < 4; ++j) {
                const int col = n0 + wn * 64 + j * 16 + lrow;
#pragma unroll
                for (int r = 0; r < 4; ++r) {
                    const int row = rowb + r;
                    float v = acc[i][j][r] + bias_s[col];
                    (((unsigned short*)C) + (long long)b * sC)
                        [(long long)row * N + col] = f2bf(v);
                }
            }
        }
    } else {  // MODE 2
        unsigned short* Cb = ((unsigned short*)C) + (long long)b * sC;
        const unsigned int* mpb = mpT + ((long long)b * S_N) * 64;
        float* rs = rowsum + (long long)b * S_N;
#pragma unroll
        for (int i = 0; i < 8; ++i) {
#pragma unroll
            for (int r = 0; r < 4; ++r) {
                const int row = m0 + wmSel * 128 + i * 16 + quad * 4 + r;
                const unsigned int* mpr = mpb + (long long)row * 64;
                float rsum = 0.0f;
#pragma unroll
                for (int j = 0; j < 4; ++j) {
                    const int col = n0 + wn * 64 + j * 16 + lrow;
                    const float v = acc[i][j][r] * scale;
                    const unsigned int wbits = mpr[col >> 5];
                    const float e = ((wbits >> (col & 31)) & 1u) ? 0.0f : __expf(v);
                    const unsigned short h = f2bf(e);
                    Cb[(long long)row * S_N + col] = h;
                    rsum += bf2f(h);
                }
                rsum += __shfl_xor(rsum, 1);
                rsum += __shfl_xor(rsum, 2);
                rsum += __shfl_xor(rsum, 4);
                rsum += __shfl_xor(rsum, 8);
                if (lrow == 0) atomicAdd(&rs[row], rsum);
            }
        }
    }
#undef PHASE
#undef STAGE_A
#undef STAGE_B
}

// attn[row][q] = bf16e[row][q] / rowsum[row]  (fp32 write to d_out attn region)
__global__ __launch_bounds__(256) void normalize_rows(
    const unsigned short* __restrict__ ebf, const float* __restrict__ rowsum,
    float* __restrict__ attn)
{
    const long long row = blockIdx.x;
    const float inv = 1.0f / rowsum[row];
    const ushort4* src = (const ushort4*)(ebf + row * S_N);
    float4* dst = (float4*)(attn + row * S_N);
    const int tid = threadIdx.x;
#pragma unroll
    for (int t = 0; t < 2; ++t) {
        ushort4 h = src[tid + t * 256];
        float4 o;
        o.x = bf2f(h.x) * inv;
        o.y = bf2f(h.y) * inv;
        o.z = bf2f(h.z) * inv;
        o.w = bf2f(h.w) * inv;
        dst[tid + t * 256] = o;
    }
}

extern "C" void kernel_launch(void* const* d_in, const int* in_sizes, int n_in,
                              void* d_out, int out_size, void* d_ws, size_t ws_size,
                              hipStream_t stream) {
    const float* Q    = (const float*)d_in[0];
    const float* K    = (const float*)d_in[1];
    const float* V    = (const float*)d_in[2];
    const int*   mask = (const int*)d_in[3];
    const float* Wq   = (const float*)d_in[4];
    const float* bq   = (const float*)d_in[5];
    const float* Wk   = (const float*)d_in[6];
    const float* bk   = (const float*)d_in[7];
    const float* Wv   = (const float*)d_in[8];
    const float* bv   = (const float*)d_in[9];

    float* out      = (float*)d_out;                              // [B,S,Dv]
    float* attn_out = out + (long long)B_N * S_N * DV_N;          // [B,S,S]

    unsigned short* Qbf  = (unsigned short*)d_ws;
    unsigned short* Kbf  = Qbf + (long long)B_N * S_N * D_N;
    unsigned short* attn_bf = Qbf;  // overlay
    unsigned short* Vbf  = Kbf + (long long)B_N * S_N * D_N;
    unsigned short* Wqbf = Vbf + (long long)B_N * S_N * D_N;
    unsigned short* Wkbf = Wqbf + (long long)A_N * D_N;
    unsigned short* Wvbf = Wkbf + (long long)A_N * D_N;
    unsigned short* Qp   = Wvbf + (long long)DV_N * D_N;   // Qp||Kp contiguous
    unsigned short* Kp   = Qp + (long long)B_N * S_N * A_N;
    unsigned short* WVt  = Kp + (long long)B_N * S_N * A_N;
    unsigned int*   mpT  = (unsigned int*)(WVt + (long long)B_N * DV_N * S_N); // 4 MB
    float*          rowsum = (float*)(mpT + (long long)B_N * S_N * 64);        // 64 KB

    const float scale = 0.044194173824159216f;  // 1/sqrt(512)

    static bool attrSet = false;
    if (!attrSet) {
        hipFuncSetAttribute(reinterpret_cast<const void*>(&gemm_nt8<0>),
                            hipFuncAttributeMaxDynamicSharedMemorySize, 131072);
        hipFuncSetAttribute(reinterpret_cast<const void*>(&gemm_nt8<2>),
                            hipFuncAttributeMaxDynamicSharedMemorySize, 131072);
        attrSet = true;
    }

    // 0) zero rowsum (ws is poisoned each call) + pack transposed mask bits
    zero_f32<<<dim3((B_N * S_N) / 256), dim3(256), 0, stream>>>(rowsum, B_N * S_N);
    pack_maskT<<<dim3(S_N / 128, S_N / 64, B_N), dim3(256), 0, stream>>>(mask, mpT);

    // 1) fp32 -> bf16: Q,K,V in one dispatch; 3 weights in one dispatch
    {
        int n4 = (int)((long long)B_N * S_N * D_N / 4);
        cvt3_f32_bf16<<<dim3((n4 + 255) / 256, 1, 3), dim3(256), 0, stream>>>(
            Q, K, V, Qbf, Kbf, Vbf, n4);
        int w4 = (int)((long long)A_N * D_N / 4);
        cvt3_f32_bf16<<<dim3((w4 + 255) / 256, 1, 3), dim3(256), 0, stream>>>(
            Wq, Wk, Wv, Wqbf, Wkbf, Wvbf, w4);
    }

    // 2) fused Q&K projections (8-phase 256^2): rows 0..16383 -> Qp, 16384.. -> Kp
    gemm_nt8<0><<<dim3(A_N / 256, (2 * B_N * S_N) / 256, 1), dim3(512), 131072, stream>>>(
        Qbf, Wqbf, Wkbf, (void*)Qp, bq, bk, nullptr, nullptr,
        2 * B_N * S_N, A_N, D_N, 0, 0, 0, 1.0f);
    // 3) WVt[b] = (V[b] @ Wv^T + bv)^T : M=Dv rows, N=S cols   (old kernel)
    gemm_nt<1><<<dim3(S_N / 128, DV_N / 128, B_N), dim3(256), 0, stream>>>(
        Wvbf, Vbf, nullptr, (void*)WVt, bv, nullptr, nullptr, nullptr,
        DV_N, S_N, D_N, 0, (long long)S_N * D_N, (long long)DV_N * S_N, 1.0f);
    // 4) e[b,k,q] = exp(scale*Kp.Qp) masked -> bf16 attn_bf; rowsum atomics (8-phase)
    gemm_nt8<2><<<dim3(S_N / 256, S_N / 256, B_N), dim3(512), 131072, stream>>>(
        Kp, Qp, nullptr, (void*)attn_bf, nullptr, nullptr, mpT, rowsum,
        S_N, S_N, A_N, (long long)S_N * A_N, (long long)S_N * A_N,
        (long long)S_N * S_N, scale);
    // 5) attn fp32 = e / rowsum -> d_out attn region
    normalize_rows<<<dim3(B_N * S_N), dim3(256), 0, stream>>>(attn_bf, rowsum, attn_out);
    // 6) selfOutput[b,k,v] = (sum_q e[b,k,q] * WVt[b,v,q]) / rowsum[b,k]  (old kernel)
    gemm_nt<3><<<dim3(DV_N / 128, S_N / 128, B_N), dim3(256), 0, stream>>>(
        attn_bf, WVt, nullptr, (void*)out, nullptr, nullptr, nullptr, rowsum,
        S_N, DV_N, S_N, (long long)S_N * S_N, (long long)DV_N * S_N,
        (long long)S_N * DV_N, 1.0f);
}